// Round 1
// baseline (326.767 us; speedup 1.0000x reference)
//
#include <hip/hip_runtime.h>

#define NB 8
#define NF 4000
#define NFRAMES (NB * NF)

// ---- filter taps (first half; symmetric). Double literals -> f32 at compile
// time, matching numpy float64 -> float32 conversion exactly.
__constant__ float c_hhp[21] = {
    0.00041447996898231424, 0.0007812505141729248, -0.0010917236836275842,
    -0.001986792567596759,  0.0020903896961562292, 0.004094057027284935,
    -0.0034025808529816698, -0.007496154127205602, 0.004972263339933064,
    0.012738791249119802,   -0.006696032689574911, -0.020694051570247052,
    0.008432436565041345,   0.03307438375870053,   -0.010018936738799522,
    -0.05423136140580825,   0.011293988915051487,  0.10020081367388213,
    -0.012120546202484579,  -0.316300210390957,    0.5124068258062764};
__constant__ float c_hlp[19] = {
    -0.0006548817007748305, 7.561994958159384e-05, 0.0020408456937895227,
    -0.0007468053532203044, -0.004350223568826493, 0.0025966428382642732,
    0.007639602282756696,   -0.006490411890149785, -0.011765804538954506,
    0.013649908479276255,   0.01636866479016021,   -0.026075976030529347,
    -0.020910294856659444,  0.04826072503231665,   0.02476784661104811,
    -0.09617846758336064,   -0.027359756709866623, 0.3148805216163004,
    0.5282734359405503};

__device__ __forceinline__ int reflidx(int i, int len) {
  if (i < 0) i = -i;
  if (i >= len) i = 2 * len - 2 - i;
  return i;
}
__device__ __forceinline__ int clampi(int i, int hi) {
  return min(max(i, 0), hi);
}

// ---- window init: np.hanning(seg+2)[1:-1] in float64, cast f32.
__global__ void win_init_kernel(float* __restrict__ win) {
  const int segs[4] = {241, 121, 61, 61};
  int k = threadIdx.x;  // 256 threads, 1 block
  for (int i = 0; i < 4; ++i) {
    float v = 0.f;
    if (k < segs[i]) {
      double ang = 2.0 * 3.14159265358979323846 * (double)(k + 1) /
                   (double)(segs[i] + 1);
      v = (float)(0.5 - 0.5 * cos(ang));
    }
    win[i * 256 + k] = v;
  }
}

// ---- QMF stage: stride-2 correlation with reflect padding, both filters.
__global__ __launch_bounds__(256) void qmf_kernel(
    const float* __restrict__ in, int len, float* __restrict__ outH,
    float* __restrict__ outL) {
  int half = len >> 1;
  int gid = blockIdx.x * 256 + threadIdx.x;
  if (gid >= NB * half) return;
  int b = gid / half;
  int nn = gid - b * half;
  const float* row = in + (size_t)b * len;
  int c = 2 * nn;
  float sh = 0.f, sl = 0.f;
  if (c >= 20 && c <= len - 21) {
    const float* p = row + c;
#pragma unroll
    for (int t = 0; t < 41; ++t) sh += p[t - 20] * c_hhp[t <= 20 ? t : 40 - t];
#pragma unroll
    for (int t = 0; t < 37; ++t) sl += p[t - 18] * c_hlp[t <= 18 ? t : 36 - t];
  } else {
#pragma unroll
    for (int t = 0; t < 41; ++t)
      sh += row[reflidx(c + t - 20, len)] * c_hhp[t <= 20 ? t : 40 - t];
#pragma unroll
    for (int t = 0; t < 37; ++t)
      sl += row[reflidx(c + t - 18, len)] * c_hlp[t <= 18 ? t : 36 - t];
  }
  outH[(size_t)b * half + nn] = sh;
  outL[(size_t)b * half + nn] = sl;
}

// ---- per-band frame kernel: one wave per frame.
template <int SEG>
__global__ __launch_bounds__(256) void band_kernel(
    const float* __restrict__ xb, int bandLen, const float* __restrict__ f0,
    float tmp_fs, const float* __restrict__ win, float* __restrict__ Aout) {
  const int wave = threadIdx.x >> 6;
  const int lane = threadIdx.x & 63;
  const int frame = blockIdx.x * 4 + wave;
  if (frame >= NFRAMES) return;
  const int b = frame / NF;
  const int n = frame - b * NF;

  float f0v = f0[frame];
  if (f0v <= 32.0f) f0v = 150.0f;
  // replicate JAX f32 op sequence exactly (no FMA contraction):
  float pitch = tmp_fs / f0v;
  int t0 = (int)(__fadd_rn(pitch, 0.5f));
  int ibias = (int)(__fadd_rn(__fmul_rn(pitch, 0.5f), 0.5f));
  float tt = __fmul_rn((float)n, 0.005f);  // FRAME_PERIOD/SR as f32
  int curr = (int)(__fadd_rn(__fmul_rn(tt, tmp_fs), 1.5f));
  int origin = curr - ibias;
  const int T1 = bandLen - 1;
  const float* row = xb + (size_t)b * bandLen;
  const int base_a = origin - t0 - 1;
  const int base_b = origin + t0 - 1;

  // pass 1: accumulate R (sym, 21) and b (6)
  float rr[21], bv[6];
#pragma unroll
  for (int i = 0; i < 21; ++i) rr[i] = 0.f;
#pragma unroll
  for (int i = 0; i < 6; ++i) bv[i] = 0.f;

  for (int k = lane; k < SEG; k += 64) {
    float wk = win[k];
    int ia = base_a + k;
    int ibb = base_b + k;
    float h[6];
    h[0] = row[clampi(ia, T1)];
    h[1] = row[clampi(ia + 1, T1)];
    h[2] = row[clampi(ia + 2, T1)];
    h[3] = row[clampi(ibb, T1)];
    h[4] = row[clampi(ibb + 1, T1)];
    h[5] = row[clampi(ibb + 2, T1)];
    float xk = row[clampi(origin + k, T1)];
    int c = 0;
#pragma unroll
    for (int p = 0; p < 6; ++p) {
      float whp = wk * h[p];
#pragma unroll
      for (int q = p; q < 6; ++q) rr[c++] += whp * h[q];
      bv[p] += whp * xk;
    }
  }
  // butterfly reduce 27 values across the wave
#pragma unroll
  for (int off = 32; off >= 1; off >>= 1) {
#pragma unroll
    for (int i = 0; i < 21; ++i) rr[i] += __shfl_xor(rr[i], off, 64);
#pragma unroll
    for (int i = 0; i < 6; ++i) bv[i] += __shfl_xor(bv[i], off, 64);
  }

  // all lanes: Cholesky of R + 1e-5 I, solve for a (redundant, avoids bcast)
  float M[6][6];
  {
    int c = 0;
#pragma unroll
    for (int p = 0; p < 6; ++p)
#pragma unroll
      for (int q = p; q < 6; ++q) {
        M[p][q] = rr[c];
        M[q][p] = rr[c];
        ++c;
      }
#pragma unroll
    for (int p = 0; p < 6; ++p) M[p][p] += 1e-5f;
  }
#pragma unroll
  for (int p = 0; p < 6; ++p) {
    float d = M[p][p];
#pragma unroll
    for (int j = 0; j < 6; ++j)
      if (j < p) d -= M[p][j] * M[p][j];
    d = sqrtf(d);
    M[p][p] = d;
    float inv = 1.0f / d;
#pragma unroll
    for (int q = 0; q < 6; ++q)
      if (q > p) {
        float s = M[q][p];
#pragma unroll
        for (int j = 0; j < 6; ++j)
          if (j < p) s -= M[q][j] * M[p][j];
        M[q][p] = s * inv;
      }
  }
  float yv[6], av[6];
#pragma unroll
  for (int p = 0; p < 6; ++p) {
    float s = bv[p];
#pragma unroll
    for (int j = 0; j < 6; ++j)
      if (j < p) s -= M[p][j] * yv[j];
    yv[p] = s / M[p][p];
  }
#pragma unroll
  for (int p = 5; p >= 0; --p) {
    float s = yv[p];
#pragma unroll
    for (int j = 0; j < 6; ++j)
      if (j > p) s -= M[j][p] * av[j];
    av[p] = s / M[p][p];
  }

  // pass 2: residual statistics
  float s1x = 0.f, s2x = 0.f, s1r = 0.f, s2r = 0.f;
  for (int k = lane; k < SEG; k += 64) {
    float wk = win[k];
    int ia = base_a + k;
    int ibb = base_b + k;
    float a0 = row[clampi(ia, T1)];
    float a1 = row[clampi(ia + 1, T1)];
    float a2 = row[clampi(ia + 2, T1)];
    float b0 = row[clampi(ibb, T1)];
    float b1 = row[clampi(ibb + 1, T1)];
    float b2 = row[clampi(ibb + 2, T1)];
    float xk = row[clampi(origin + k, T1)];
    float hax = a0 * av[0] + a1 * av[1] + a2 * av[2] + b0 * av[3] +
                b1 * av[4] + b2 * av[5];
    float r = xk - hax;
    float ws = sqrtf(wk);
    s1x += ws * xk;
    s2x += wk * xk * xk;
    s1r += ws * r;
    s2r += wk * r * r;
  }
#pragma unroll
  for (int off = 32; off >= 1; off >>= 1) {
    s1x += __shfl_xor(s1x, off, 64);
    s2x += __shfl_xor(s2x, off, 64);
    s1r += __shfl_xor(s1r, off, 64);
    s2r += __shfl_xor(s2r, off, 64);
  }
  if (lane == 0) {
    const float nf = (float)SEG;
    float vx = (s2x - s1x * s1x / nf) / (nf - 1.0f);
    float vr = (s2r - s1r * s1r / nf) / (nf - 1.0f);
    float sx = sqrtf(fmaxf(vx, 0.f));
    float sr = sqrtf(fmaxf(vr, 0.f));
    Aout[frame] = sr / (sx + 1e-16f);
  }
}

// ---- per-frame log nodes: y0[4], dy[4]
__global__ __launch_bounds__(256) void log_kernel(const float* __restrict__ A,
                                                  float* __restrict__ y0s,
                                                  float* __restrict__ dys) {
  int f = blockIdx.x * 256 + threadIdx.x;
  if (f >= NFRAMES) return;
  float l0 = logf(A[0 * NFRAMES + f]);  // band0: node 8000 Hz
  float l1 = logf(A[1 * NFRAMES + f]);  // 4000
  float l2 = logf(A[2 * NFRAMES + f]);  // 2000
  float l3 = logf(A[3 * NFRAMES + f]);  // 0 & 1000 (duplicated)
  y0s[f * 4 + 0] = l3;
  y0s[f * 4 + 1] = l3;
  y0s[f * 4 + 2] = l2;
  y0s[f * 4 + 3] = l1;
  dys[f * 4 + 0] = 0.f;
  dys[f * 4 + 1] = l2 - l3;
  dys[f * 4 + 2] = l1 - l2;
  dys[f * 4 + 3] = l0 - l1;
}

// ---- interpolate to 513 bins, exp
__global__ __launch_bounds__(256) void interp_kernel(
    const float* __restrict__ y0s, const float* __restrict__ dys,
    float* __restrict__ out) {
  int gid = blockIdx.x * 256 + threadIdx.x;
  const int total = NFRAMES * 513;
  if (gid >= total) return;
  int f = gid / 513;
  int k = gid - f * 513;
  float freq = (float)k * 15.625f;  // exact
  int idx = (freq > 1000.f) + (freq > 2000.f) + (freq > 4000.f);
  const float x0[4] = {0.f, 1000.f, 2000.f, 4000.f};
  const float dxv[4] = {1000.f, 1000.f, 2000.f, 4000.f};
  float w = (freq - x0[idx]) / dxv[idx];
  out[gid] = expf(y0s[f * 4 + idx] + w * dys[f * 4 + idx]);
}

extern "C" void kernel_launch(void* const* d_in, const int* in_sizes, int n_in,
                              void* d_out, int out_size, void* d_ws,
                              size_t ws_size, hipStream_t stream) {
  const float* x = (const float*)d_in[0];    // (8, 320000)
  const float* f0 = (const float*)d_in[1];   // (8, 4000)
  float* out = (float*)d_out;                // (8, 4000, 513)
  float* ws = (float*)d_ws;

  // workspace layout (floats)
  float* hx0 = ws + 0;             // 8*160000
  float* lx0 = hx0 + 1280000;      // 8*160000
  float* hx1 = lx0 + 1280000;      // 8*80000
  float* lx1 = hx1 + 640000;       // 8*80000
  float* hx2 = lx1 + 640000;       // 8*40000
  float* lx2 = hx2 + 320000;       // 8*40000
  float* Aarr = lx2 + 320000;      // 4*32000  [band][frame]
  float* y0s = Aarr + 4 * NFRAMES; // 32000*4
  float* dys = y0s + 4 * NFRAMES;  // 32000*4
  float* win = dys + 4 * NFRAMES;  // 4*256
  (void)ws_size;

  hipLaunchKernelGGL(win_init_kernel, dim3(1), dim3(256), 0, stream, win);

  // QMF cascade
  {
    int len = 320000, half = len / 2;
    int blocks = (NB * half + 255) / 256;
    hipLaunchKernelGGL(qmf_kernel, dim3(blocks), dim3(256), 0, stream, x, len,
                       hx0, lx0);
  }
  {
    int len = 160000, half = len / 2;
    int blocks = (NB * half + 255) / 256;
    hipLaunchKernelGGL(qmf_kernel, dim3(blocks), dim3(256), 0, stream, lx0,
                       len, hx1, lx1);
  }
  {
    int len = 80000, half = len / 2;
    int blocks = (NB * half + 255) / 256;
    hipLaunchKernelGGL(qmf_kernel, dim3(blocks), dim3(256), 0, stream, lx1,
                       len, hx2, lx2);
  }

  // band kernels: one wave per frame, 4 waves per block
  const int bblocks = NFRAMES / 4;
  hipLaunchKernelGGL(band_kernel<241>, dim3(bblocks), dim3(256), 0, stream,
                     hx0, 160000, f0, 8000.0f, win + 0 * 256, Aarr + 0 * NFRAMES);
  hipLaunchKernelGGL(band_kernel<121>, dim3(bblocks), dim3(256), 0, stream,
                     hx1, 80000, f0, 4000.0f, win + 1 * 256, Aarr + 1 * NFRAMES);
  hipLaunchKernelGGL(band_kernel<61>, dim3(bblocks), dim3(256), 0, stream,
                     hx2, 40000, f0, 2000.0f, win + 2 * 256, Aarr + 2 * NFRAMES);
  hipLaunchKernelGGL(band_kernel<61>, dim3(bblocks), dim3(256), 0, stream,
                     lx2, 40000, f0, 2000.0f, win + 3 * 256, Aarr + 3 * NFRAMES);

  // log nodes + interp
  hipLaunchKernelGGL(log_kernel, dim3((NFRAMES + 255) / 256), dim3(256), 0,
                     stream, Aarr, y0s, dys);
  {
    int total = NFRAMES * 513;
    hipLaunchKernelGGL(interp_kernel, dim3((total + 255) / 256), dim3(256), 0,
                       stream, y0s, dys, out);
  }
}

// Round 2
// 150.341 us; speedup vs baseline: 2.1735x; 2.1735x over previous
//
#include <hip/hip_runtime.h>

#define NB 8
#define NF 4000
#define NFRAMES (NB * NF)

// ---- filter taps (first half; symmetric). Double literals -> f32 at compile
// time, matching numpy float64 -> float32 conversion exactly.
__constant__ float c_hhp[21] = {
    0.00041447996898231424, 0.0007812505141729248, -0.0010917236836275842,
    -0.001986792567596759,  0.0020903896961562292, 0.004094057027284935,
    -0.0034025808529816698, -0.007496154127205602, 0.004972263339933064,
    0.012738791249119802,   -0.006696032689574911, -0.020694051570247052,
    0.008432436565041345,   0.03307438375870053,   -0.010018936738799522,
    -0.05423136140580825,   0.011293988915051487,  0.10020081367388213,
    -0.012120546202484579,  -0.316300210390957,    0.5124068258062764};
__constant__ float c_hlp[19] = {
    -0.0006548817007748305, 7.561994958159384e-05, 0.0020408456937895227,
    -0.0007468053532203044, -0.004350223568826493, 0.0025966428382642732,
    0.007639602282756696,   -0.006490411890149785, -0.011765804538954506,
    0.013649908479276255,   0.01636866479016021,   -0.026075976030529347,
    -0.020910294856659444,  0.04826072503231665,   0.02476784661104811,
    -0.09617846758336064,   -0.027359756709866623, 0.3148805216163004,
    0.5282734359405503};

__device__ __forceinline__ int reflidx(int i, int len) {
  if (i < 0) i = -i;
  if (i >= len) i = 2 * len - 2 - i;
  return i;
}
__device__ __forceinline__ int clampi(int i, int hi) {
  return min(max(i, 0), hi);
}

// ---- window init: np.hanning(seg+2)[1:-1] in float64, cast f32; also sqrt.
__global__ void win_init_kernel(float* __restrict__ win,
                                float* __restrict__ wsq) {
  const int segs[4] = {241, 121, 61, 61};
  int k = threadIdx.x;  // 256 threads, 1 block
  for (int i = 0; i < 4; ++i) {
    float v = 0.f;
    if (k < segs[i]) {
      double ang = 2.0 * 3.14159265358979323846 * (double)(k + 1) /
                   (double)(segs[i] + 1);
      v = (float)(0.5 - 0.5 * cos(ang));
    }
    win[i * 256 + k] = v;
    wsq[i * 256 + k] = sqrtf(v);
  }
}

// ---- QMF stage: stride-2 correlation with reflect padding, both filters.
__global__ __launch_bounds__(256) void qmf_kernel(
    const float* __restrict__ in, int len, float* __restrict__ outH,
    float* __restrict__ outL) {
  int half = len >> 1;
  int gid = blockIdx.x * 256 + threadIdx.x;
  if (gid >= NB * half) return;
  int b = gid / half;
  int nn = gid - b * half;
  const float* row = in + (size_t)b * len;
  int c = 2 * nn;
  float sh = 0.f, sl = 0.f;
  if (c >= 20 && c <= len - 21) {
    const float* p = row + c;
#pragma unroll
    for (int t = 0; t < 41; ++t) sh += p[t - 20] * c_hhp[t <= 20 ? t : 40 - t];
#pragma unroll
    for (int t = 0; t < 37; ++t) sl += p[t - 18] * c_hlp[t <= 18 ? t : 36 - t];
  } else {
#pragma unroll
    for (int t = 0; t < 41; ++t)
      sh += row[reflidx(c + t - 20, len)] * c_hhp[t <= 20 ? t : 40 - t];
#pragma unroll
    for (int t = 0; t < 37; ++t)
      sl += row[reflidx(c + t - 18, len)] * c_hlp[t <= 18 ? t : 36 - t];
  }
  outH[(size_t)b * half + nn] = sh;
  outL[(size_t)b * half + nn] = sl;
}

// ---- accumulation loop (single pass; 35 sums)
template <int SEG, int GS, bool CLAMP>
__device__ __forceinline__ void acc_loop(
    const float* __restrict__ row, int T1, int base_a, int base_b, int origin,
    int sub, const float* __restrict__ win, const float* __restrict__ wsq,
    float rr[21], float bv[6], float gv[6], float& sxx, float& s1x) {
  for (int k = sub; k < SEG; k += GS) {
    float wk = win[k];
    float wsk = wsq[k];
    int ia = base_a + k, ib = base_b + k, ig = origin + k;
    float h[6], x;
    if (CLAMP) {
      h[0] = row[clampi(ia, T1)];
      h[1] = row[clampi(ia + 1, T1)];
      h[2] = row[clampi(ia + 2, T1)];
      h[3] = row[clampi(ib, T1)];
      h[4] = row[clampi(ib + 1, T1)];
      h[5] = row[clampi(ib + 2, T1)];
      x = row[clampi(ig, T1)];
    } else {
      h[0] = row[ia];
      h[1] = row[ia + 1];
      h[2] = row[ia + 2];
      h[3] = row[ib];
      h[4] = row[ib + 1];
      h[5] = row[ib + 2];
      x = row[ig];
    }
    sxx += wk * x * x;
    s1x += wsk * x;
    int c = 0;
#pragma unroll
    for (int p = 0; p < 6; ++p) {
      float whp = wk * h[p];
      gv[p] += wsk * h[p];
      bv[p] += whp * x;
#pragma unroll
      for (int q = p; q < 6; ++q) rr[c++] += whp * h[q];
    }
  }
}

// ---- per-band frame kernel: GS lanes per frame, 256-thread blocks.
template <int SEG, int LGS>
__global__ __launch_bounds__(256) void band_kernel(
    const float* __restrict__ xb, int bandLen, const float* __restrict__ f0,
    float tmp_fs, const float* __restrict__ win, const float* __restrict__ wsq,
    float* __restrict__ Aout) {
  constexpr int GS = 1 << LGS;
  constexpr int FPB = 256 / GS;
  const int sub = threadIdx.x & (GS - 1);
  const int frame = blockIdx.x * FPB + (threadIdx.x >> LGS);
  if (frame >= NFRAMES) return;
  const int b = frame / NF;
  const int n = frame - b * NF;

  float f0v = f0[frame];
  if (f0v <= 32.0f) f0v = 150.0f;
  // replicate JAX f32 op sequence exactly (no FMA contraction):
  float pitch = tmp_fs / f0v;
  int t0 = (int)(__fadd_rn(pitch, 0.5f));
  int ibias = (int)(__fadd_rn(__fmul_rn(pitch, 0.5f), 0.5f));
  float tt = __fmul_rn((float)n, 0.005f);  // FRAME_PERIOD/SR as f32
  int curr = (int)(__fadd_rn(__fmul_rn(tt, tmp_fs), 1.5f));
  int origin = curr - ibias;
  const int T1 = bandLen - 1;
  const float* row = xb + (size_t)b * bandLen;
  const int base_a = origin - t0 - 1;
  const int base_b = origin + t0 - 1;

  float rr[21], bv[6], gv[6], sxx = 0.f, s1x = 0.f;
#pragma unroll
  for (int i = 0; i < 21; ++i) rr[i] = 0.f;
#pragma unroll
  for (int i = 0; i < 6; ++i) bv[i] = 0.f;
#pragma unroll
  for (int i = 0; i < 6; ++i) gv[i] = 0.f;

  const bool fast = (base_a >= 0) && (base_b + SEG + 1 <= T1);
  if (fast)
    acc_loop<SEG, GS, false>(row, T1, base_a, base_b, origin, sub, win, wsq,
                             rr, bv, gv, sxx, s1x);
  else
    acc_loop<SEG, GS, true>(row, T1, base_a, base_b, origin, sub, win, wsq,
                            rr, bv, gv, sxx, s1x);

  // butterfly reduce 35 values within the GS-lane group
#pragma unroll
  for (int off = GS / 2; off >= 1; off >>= 1) {
#pragma unroll
    for (int i = 0; i < 21; ++i) rr[i] += __shfl_xor(rr[i], off, 64);
#pragma unroll
    for (int i = 0; i < 6; ++i) bv[i] += __shfl_xor(bv[i], off, 64);
#pragma unroll
    for (int i = 0; i < 6; ++i) gv[i] += __shfl_xor(gv[i], off, 64);
    sxx += __shfl_xor(sxx, off, 64);
    s1x += __shfl_xor(s1x, off, 64);
  }

  // Cholesky of R + 1e-5 I, solve for a (redundant across group lanes)
  float M[6][6];
  {
    int c = 0;
#pragma unroll
    for (int p = 0; p < 6; ++p)
#pragma unroll
      for (int q = p; q < 6; ++q) {
        M[p][q] = rr[c];
        M[q][p] = rr[c];
        ++c;
      }
#pragma unroll
    for (int p = 0; p < 6; ++p) M[p][p] += 1e-5f;
  }
#pragma unroll
  for (int p = 0; p < 6; ++p) {
    float d = M[p][p];
#pragma unroll
    for (int j = 0; j < 6; ++j)
      if (j < p) d -= M[p][j] * M[p][j];
    d = sqrtf(d);
    M[p][p] = d;
    float inv = 1.0f / d;
#pragma unroll
    for (int q = 0; q < 6; ++q)
      if (q > p) {
        float s = M[q][p];
#pragma unroll
        for (int j = 0; j < 6; ++j)
          if (j < p) s -= M[q][j] * M[p][j];
        M[q][p] = s * inv;
      }
  }
  float yv[6], av[6];
#pragma unroll
  for (int p = 0; p < 6; ++p) {
    float s = bv[p];
#pragma unroll
    for (int j = 0; j < 6; ++j)
      if (j < p) s -= M[p][j] * yv[j];
    yv[p] = s / M[p][p];
  }
#pragma unroll
  for (int p = 5; p >= 0; --p) {
    float s = yv[p];
#pragma unroll
    for (int j = 0; j < 6; ++j)
      if (j > p) s -= M[j][p] * av[j];
    av[p] = s / M[p][p];
  }

  // residual stats via algebra:
  //   s2r = Sxx - 2 a.b + a'Ra ;  s1r = S1x - a.g   (R without eps)
  float adotb = 0.f, adotg = 0.f, quad = 0.f;
  {
    int c = 0;
#pragma unroll
    for (int p = 0; p < 6; ++p) {
      adotb += av[p] * bv[p];
      adotg += av[p] * gv[p];
#pragma unroll
      for (int q = p; q < 6; ++q) {
        float t = av[p] * av[q] * rr[c++];
        quad += (q == p) ? t : 2.f * t;
      }
    }
  }
  if (sub == 0) {
    float s2r = sxx - 2.f * adotb + quad;
    float s1r = s1x - adotg;
    const float nf = (float)SEG;
    float vx = (sxx - s1x * s1x / nf) / (nf - 1.0f);
    float vr = (s2r - s1r * s1r / nf) / (nf - 1.0f);
    float sx = sqrtf(fmaxf(vx, 0.f));
    float sr = sqrtf(fmaxf(vr, 0.f));
    Aout[frame] = sr / (sx + 1e-16f);
  }
}

// ---- per-frame log nodes: y0[4], dy[4]
__global__ __launch_bounds__(256) void log_kernel(const float* __restrict__ A,
                                                  float* __restrict__ y0s,
                                                  float* __restrict__ dys) {
  int f = blockIdx.x * 256 + threadIdx.x;
  if (f >= NFRAMES) return;
  float l0 = logf(A[0 * NFRAMES + f]);  // band0: node 8000 Hz
  float l1 = logf(A[1 * NFRAMES + f]);  // 4000
  float l2 = logf(A[2 * NFRAMES + f]);  // 2000
  float l3 = logf(A[3 * NFRAMES + f]);  // 0 & 1000 (duplicated)
  y0s[f * 4 + 0] = l3;
  y0s[f * 4 + 1] = l3;
  y0s[f * 4 + 2] = l2;
  y0s[f * 4 + 3] = l1;
  dys[f * 4 + 0] = 0.f;
  dys[f * 4 + 1] = l2 - l3;
  dys[f * 4 + 2] = l1 - l2;
  dys[f * 4 + 3] = l0 - l1;
}

// ---- interpolate to 513 bins, exp
__global__ __launch_bounds__(256) void interp_kernel(
    const float* __restrict__ y0s, const float* __restrict__ dys,
    float* __restrict__ out) {
  int gid = blockIdx.x * 256 + threadIdx.x;
  const int total = NFRAMES * 513;
  if (gid >= total) return;
  int f = gid / 513;
  int k = gid - f * 513;
  float freq = (float)k * 15.625f;  // exact
  int idx = (freq > 1000.f) + (freq > 2000.f) + (freq > 4000.f);
  const float x0[4] = {0.f, 1000.f, 2000.f, 4000.f};
  const float dxv[4] = {1000.f, 1000.f, 2000.f, 4000.f};
  float w = (freq - x0[idx]) / dxv[idx];
  out[gid] = expf(y0s[f * 4 + idx] + w * dys[f * 4 + idx]);
}

extern "C" void kernel_launch(void* const* d_in, const int* in_sizes, int n_in,
                              void* d_out, int out_size, void* d_ws,
                              size_t ws_size, hipStream_t stream) {
  const float* x = (const float*)d_in[0];    // (8, 320000)
  const float* f0 = (const float*)d_in[1];   // (8, 4000)
  float* out = (float*)d_out;                // (8, 4000, 513)
  float* ws = (float*)d_ws;

  // workspace layout (floats)
  float* hx0 = ws + 0;             // 8*160000
  float* lx0 = hx0 + 1280000;      // 8*160000
  float* hx1 = lx0 + 1280000;      // 8*80000
  float* lx1 = hx1 + 640000;       // 8*80000
  float* hx2 = lx1 + 640000;       // 8*40000
  float* lx2 = hx2 + 320000;       // 8*40000
  float* Aarr = lx2 + 320000;      // 4*32000  [band][frame]
  float* y0s = Aarr + 4 * NFRAMES; // 32000*4
  float* dys = y0s + 4 * NFRAMES;  // 32000*4
  float* win = dys + 4 * NFRAMES;  // 4*256
  float* wsq = win + 4 * 256;      // 4*256
  (void)ws_size;

  hipLaunchKernelGGL(win_init_kernel, dim3(1), dim3(256), 0, stream, win, wsq);

  // QMF cascade
  {
    int len = 320000, half = len / 2;
    int blocks = (NB * half + 255) / 256;
    hipLaunchKernelGGL(qmf_kernel, dim3(blocks), dim3(256), 0, stream, x, len,
                       hx0, lx0);
  }
  {
    int len = 160000, half = len / 2;
    int blocks = (NB * half + 255) / 256;
    hipLaunchKernelGGL(qmf_kernel, dim3(blocks), dim3(256), 0, stream, lx0,
                       len, hx1, lx1);
  }
  {
    int len = 80000, half = len / 2;
    int blocks = (NB * half + 255) / 256;
    hipLaunchKernelGGL(qmf_kernel, dim3(blocks), dim3(256), 0, stream, lx1,
                       len, hx2, lx2);
  }

  // band kernels: GS=16 lanes/frame for seg 241/121 (16 frames per block),
  // GS=8 for seg 61 (32 frames per block)
  hipLaunchKernelGGL((band_kernel<241, 4>), dim3(NFRAMES / 16), dim3(256), 0,
                     stream, hx0, 160000, f0, 8000.0f, win + 0 * 256,
                     wsq + 0 * 256, Aarr + 0 * NFRAMES);
  hipLaunchKernelGGL((band_kernel<121, 4>), dim3(NFRAMES / 16), dim3(256), 0,
                     stream, hx1, 80000, f0, 4000.0f, win + 1 * 256,
                     wsq + 1 * 256, Aarr + 1 * NFRAMES);
  hipLaunchKernelGGL((band_kernel<61, 3>), dim3(NFRAMES / 32), dim3(256), 0,
                     stream, hx2, 40000, f0, 2000.0f, win + 2 * 256,
                     wsq + 2 * 256, Aarr + 2 * NFRAMES);
  hipLaunchKernelGGL((band_kernel<61, 3>), dim3(NFRAMES / 32), dim3(256), 0,
                     stream, lx2, 40000, f0, 2000.0f, win + 3 * 256,
                     wsq + 3 * 256, Aarr + 3 * NFRAMES);

  // log nodes + interp
  hipLaunchKernelGGL(log_kernel, dim3((NFRAMES + 255) / 256), dim3(256), 0,
                     stream, Aarr, y0s, dys);
  {
    int total = NFRAMES * 513;
    hipLaunchKernelGGL(interp_kernel, dim3((total + 255) / 256), dim3(256), 0,
                       stream, y0s, dys, out);
  }
}

// Round 3
// 87.721 us; speedup vs baseline: 3.7251x; 1.7139x over previous
//
#include <hip/hip_runtime.h>
#include <math.h>

#define NB 8
#define NF 4000
#define NFRAMES (NB * NF)

// ---- filter taps (first half; symmetric). Double literals -> f32 at compile
// time, matching numpy float64 -> float32 conversion exactly.
__constant__ float c_hhp[21] = {
    0.00041447996898231424, 0.0007812505141729248, -0.0010917236836275842,
    -0.001986792567596759,  0.0020903896961562292, 0.004094057027284935,
    -0.0034025808529816698, -0.007496154127205602, 0.004972263339933064,
    0.012738791249119802,   -0.006696032689574911, -0.020694051570247052,
    0.008432436565041345,   0.03307438375870053,   -0.010018936738799522,
    -0.05423136140580825,   0.011293988915051487,  0.10020081367388213,
    -0.012120546202484579,  -0.316300210390957,    0.5124068258062764};
__constant__ float c_hlp[19] = {
    -0.0006548817007748305, 7.561994958159384e-05, 0.0020408456937895227,
    -0.0007468053532203044, -0.004350223568826493, 0.0025966428382642732,
    0.007639602282756696,   -0.006490411890149785, -0.011765804538954506,
    0.013649908479276255,   0.01636866479016021,   -0.026075976030529347,
    -0.020910294856659444,  0.04826072503231665,   0.02476784661104811,
    -0.09617846758336064,   -0.027359756709866623, 0.3148805216163004,
    0.5282734359405503};

__device__ __forceinline__ int reflidx(int i, int len) {
  if (i < 0) i = -i;
  if (i >= len) i = 2 * len - 2 - i;
  return i;
}
__device__ __forceinline__ int clampi(int i, int hi) {
  return min(max(i, 0), hi);
}

// ---- QMF stage: stride-2 correlation with reflect padding, both filters.
// If wtab != null, one extra block (gid >= NB*half) initializes the
// (hanning, sqrt(hanning)) tables instead.
__global__ __launch_bounds__(256) void qmf_kernel(
    const float* __restrict__ in, int len, float* __restrict__ outH,
    float* __restrict__ outL, float2* __restrict__ wtab) {
  int half = len >> 1;
  int gid = blockIdx.x * 256 + threadIdx.x;
  if (gid >= NB * half) {
    if (wtab) {
      const int segs[4] = {241, 121, 61, 61};
      int k = threadIdx.x;
      for (int i = 0; i < 4; ++i) {
        float v = 0.f;
        if (k < segs[i]) {
          double ang = 2.0 * 3.14159265358979323846 * (double)(k + 1) /
                       (double)(segs[i] + 1);
          v = (float)(0.5 - 0.5 * cos(ang));
        }
        wtab[i * 256 + k] = make_float2(v, sqrtf(v));
      }
    }
    return;
  }
  int b = gid / half;
  int nn = gid - b * half;
  const float* row = in + (size_t)b * len;
  int c = 2 * nn;
  float sh = 0.f, sl = 0.f;
  if (c >= 20 && c <= len - 22) {
    // fast path: 21 float2 loads cover x[c-20 .. c+21]; HP uses v[0..40],
    // LP uses v[2..38].
    const float2* p2 = reinterpret_cast<const float2*>(row + (c - 20));
    float v[42];
#pragma unroll
    for (int j = 0; j < 21; ++j) {
      float2 t = p2[j];
      v[2 * j] = t.x;
      v[2 * j + 1] = t.y;
    }
#pragma unroll
    for (int t = 0; t < 41; ++t) sh += v[t] * c_hhp[t <= 20 ? t : 40 - t];
#pragma unroll
    for (int t = 0; t < 37; ++t) sl += v[t + 2] * c_hlp[t <= 18 ? t : 36 - t];
  } else {
#pragma unroll
    for (int t = 0; t < 41; ++t)
      sh += row[reflidx(c + t - 20, len)] * c_hhp[t <= 20 ? t : 40 - t];
#pragma unroll
    for (int t = 0; t < 37; ++t)
      sl += row[reflidx(c + t - 18, len)] * c_hlp[t <= 18 ? t : 36 - t];
  }
  outH[(size_t)b * half + nn] = sh;
  outL[(size_t)b * half + nn] = sl;
}

// ---- accumulation loop (single pass; 35 sums)
template <int SEG, int GS, bool CLAMP>
__device__ __forceinline__ void acc_loop(
    const float* __restrict__ row, int T1, int base_a, int base_b, int origin,
    int sub, const float2* __restrict__ wtab, float rr[21], float bv[6],
    float gv[6], float& sxx, float& s1x) {
  for (int k = sub; k < SEG; k += GS) {
    float2 wp = wtab[k];
    float wk = wp.x, wsk = wp.y;
    int ia = base_a + k, ib = base_b + k, ig = origin + k;
    float h[6], x;
    if (CLAMP) {
      h[0] = row[clampi(ia, T1)];
      h[1] = row[clampi(ia + 1, T1)];
      h[2] = row[clampi(ia + 2, T1)];
      h[3] = row[clampi(ib, T1)];
      h[4] = row[clampi(ib + 1, T1)];
      h[5] = row[clampi(ib + 2, T1)];
      x = row[clampi(ig, T1)];
    } else {
      h[0] = row[ia];
      h[1] = row[ia + 1];
      h[2] = row[ia + 2];
      h[3] = row[ib];
      h[4] = row[ib + 1];
      h[5] = row[ib + 2];
      x = row[ig];
    }
    sxx += wk * x * x;
    s1x += wsk * x;
    int c = 0;
#pragma unroll
    for (int p = 0; p < 6; ++p) {
      float whp = wk * h[p];
      gv[p] += wsk * h[p];
      bv[p] += whp * x;
#pragma unroll
      for (int q = p; q < 6; ++q) rr[c++] += whp * h[q];
    }
  }
}

// ---- per-band frame body: GS lanes per frame.
template <int SEG, int LGS>
__device__ __forceinline__ void band_body(
    const float* __restrict__ xb, int bandLen, const float* __restrict__ f0,
    float tmp_fs, const float2* __restrict__ wtab, float* __restrict__ Aout,
    int blk) {
  constexpr int GS = 1 << LGS;
  constexpr int FPB = 256 / GS;
  const int sub = threadIdx.x & (GS - 1);
  const int frame = blk * FPB + (threadIdx.x >> LGS);
  const int b = frame / NF;
  const int n = frame - b * NF;

  float f0v = f0[frame];
  if (f0v <= 32.0f) f0v = 150.0f;
  // replicate JAX f32 op sequence exactly (no FMA contraction):
  float pitch = tmp_fs / f0v;
  int t0 = (int)(__fadd_rn(pitch, 0.5f));
  int ibias = (int)(__fadd_rn(__fmul_rn(pitch, 0.5f), 0.5f));
  float tt = __fmul_rn((float)n, 0.005f);  // FRAME_PERIOD/SR as f32
  int curr = (int)(__fadd_rn(__fmul_rn(tt, tmp_fs), 1.5f));
  int origin = curr - ibias;
  const int T1 = bandLen - 1;
  const float* row = xb + (size_t)b * bandLen;
  const int base_a = origin - t0 - 1;
  const int base_b = origin + t0 - 1;

  float rr[21], bv[6], gv[6], sxx = 0.f, s1x = 0.f;
#pragma unroll
  for (int i = 0; i < 21; ++i) rr[i] = 0.f;
#pragma unroll
  for (int i = 0; i < 6; ++i) bv[i] = 0.f;
#pragma unroll
  for (int i = 0; i < 6; ++i) gv[i] = 0.f;

  const bool fast = (base_a >= 0) && (base_b + SEG + 1 <= T1);
  if (fast)
    acc_loop<SEG, GS, false>(row, T1, base_a, base_b, origin, sub, wtab, rr,
                             bv, gv, sxx, s1x);
  else
    acc_loop<SEG, GS, true>(row, T1, base_a, base_b, origin, sub, wtab, rr,
                            bv, gv, sxx, s1x);

  // butterfly reduce 35 values within the GS-lane group
#pragma unroll
  for (int off = GS / 2; off >= 1; off >>= 1) {
#pragma unroll
    for (int i = 0; i < 21; ++i) rr[i] += __shfl_xor(rr[i], off, 64);
#pragma unroll
    for (int i = 0; i < 6; ++i) bv[i] += __shfl_xor(bv[i], off, 64);
#pragma unroll
    for (int i = 0; i < 6; ++i) gv[i] += __shfl_xor(gv[i], off, 64);
    sxx += __shfl_xor(sxx, off, 64);
    s1x += __shfl_xor(s1x, off, 64);
  }

  // Cholesky of R + 1e-5 I, solve for a (redundant across group lanes)
  float M[6][6], invd[6];
  {
    int c = 0;
#pragma unroll
    for (int p = 0; p < 6; ++p)
#pragma unroll
      for (int q = p; q < 6; ++q) {
        M[p][q] = rr[c];
        M[q][p] = rr[c];
        ++c;
      }
#pragma unroll
    for (int p = 0; p < 6; ++p) M[p][p] += 1e-5f;
  }
#pragma unroll
  for (int p = 0; p < 6; ++p) {
    float d = M[p][p];
#pragma unroll
    for (int j = 0; j < 6; ++j)
      if (j < p) d -= M[p][j] * M[p][j];
    d = sqrtf(d);
    M[p][p] = d;
    float inv = 1.0f / d;
    invd[p] = inv;
#pragma unroll
    for (int q = 0; q < 6; ++q)
      if (q > p) {
        float s = M[q][p];
#pragma unroll
        for (int j = 0; j < 6; ++j)
          if (j < p) s -= M[q][j] * M[p][j];
        M[q][p] = s * inv;
      }
  }
  float yv[6], av[6];
#pragma unroll
  for (int p = 0; p < 6; ++p) {
    float s = bv[p];
#pragma unroll
    for (int j = 0; j < 6; ++j)
      if (j < p) s -= M[p][j] * yv[j];
    yv[p] = s * invd[p];
  }
#pragma unroll
  for (int p = 5; p >= 0; --p) {
    float s = yv[p];
#pragma unroll
    for (int j = 0; j < 6; ++j)
      if (j > p) s -= M[j][p] * av[j];
    av[p] = s * invd[p];
  }

  // residual stats via exact expansion (valid for ANY a):
  //   s2r = Sxx - 2 a.b + a'Ra ;  s1r = S1x - a.g   (R without eps)
  float adotb = 0.f, adotg = 0.f, quad = 0.f;
  {
    int c = 0;
#pragma unroll
    for (int p = 0; p < 6; ++p) {
      adotb += av[p] * bv[p];
      adotg += av[p] * gv[p];
#pragma unroll
      for (int q = p; q < 6; ++q) {
        float t = av[p] * av[q] * rr[c++];
        quad += (q == p) ? t : 2.f * t;
      }
    }
  }
  if (sub == 0) {
    float s2r = sxx - 2.f * adotb + quad;
    float s1r = s1x - adotg;
    const float nf = (float)SEG;
    float vx = (sxx - s1x * s1x / nf) / (nf - 1.0f);
    float vr = (s2r - s1r * s1r / nf) / (nf - 1.0f);
    float sx = sqrtf(fmaxf(vx, 0.f));
    float sr = sqrtf(fmaxf(vr, 0.f));
    Aout[frame] = sr / (sx + 1e-16f);
  }
}

// ---- all 4 bands in one launch. Blocks: [0,1000) band0 GS=8, [1000,2000)
// band1 GS=8, [2000,2500) band2 GS=4, [2500,3000) band3 GS=4.
__global__ __launch_bounds__(256) void bands_kernel(
    const float* __restrict__ hx0, const float* __restrict__ hx1,
    const float* __restrict__ hx2, const float* __restrict__ lx2,
    const float* __restrict__ f0, const float2* __restrict__ wtab,
    float* __restrict__ Aarr) {
  int blk = blockIdx.x;
  if (blk < 1000) {
    band_body<241, 3>(hx0, 160000, f0, 8000.0f, wtab + 0 * 256,
                      Aarr + 0 * NFRAMES, blk);
  } else if (blk < 2000) {
    band_body<121, 3>(hx1, 80000, f0, 4000.0f, wtab + 1 * 256,
                      Aarr + 1 * NFRAMES, blk - 1000);
  } else if (blk < 2500) {
    band_body<61, 2>(hx2, 40000, f0, 2000.0f, wtab + 2 * 256,
                     Aarr + 2 * NFRAMES, blk - 2000);
  } else {
    band_body<61, 2>(lx2, 40000, f0, 2000.0f, wtab + 3 * 256,
                     Aarr + 3 * NFRAMES, blk - 2500);
  }
}

// ---- fused log + interpolate + exp: one wave per frame, 4 waves/block.
__global__ __launch_bounds__(256) void interp_kernel(
    const float* __restrict__ A, float* __restrict__ out) {
  const int wave = threadIdx.x >> 6;
  const int lane = threadIdx.x & 63;
  const int f = blockIdx.x * 4 + wave;
  float l0 = __logf(A[0 * NFRAMES + f]);  // band0: 8000 Hz node
  float l1 = __logf(A[1 * NFRAMES + f]);  // 4000
  float l2 = __logf(A[2 * NFRAMES + f]);  // 2000
  float l3 = __logf(A[3 * NFRAMES + f]);  // 0 & 1000 (duplicated)
  float d1 = l2 - l3, d2 = l1 - l2, d3 = l0 - l1;
  float* orow = out + (size_t)f * 513;
  for (int k = lane; k < 513; k += 64) {
    // freq = k*15.625; idx boundaries at k = 64 / 128 / 256 (exact).
    float y0, dy, c;
    int k0;
    if (k <= 64) {
      y0 = l3; dy = 0.f; k0 = 0; c = 0.015625f;        // 1/64
    } else if (k <= 128) {
      y0 = l3; dy = d1; k0 = 64; c = 0.015625f;        // 1/64
    } else if (k <= 256) {
      y0 = l2; dy = d2; k0 = 128; c = 0.0078125f;      // 1/128
    } else {
      y0 = l1; dy = d3; k0 = 256; c = 0.00390625f;     // 1/256
    }
    float w = (float)(k - k0) * c;  // exact (matches f64-computed _WTS)
    orow[k] = __expf(y0 + w * dy);
  }
}

extern "C" void kernel_launch(void* const* d_in, const int* in_sizes, int n_in,
                              void* d_out, int out_size, void* d_ws,
                              size_t ws_size, hipStream_t stream) {
  const float* x = (const float*)d_in[0];   // (8, 320000)
  const float* f0 = (const float*)d_in[1];  // (8, 4000)
  float* out = (float*)d_out;               // (8, 4000, 513)
  float* ws = (float*)d_ws;

  // workspace layout (floats)
  float* hx0 = ws + 0;              // 8*160000
  float* lx0 = hx0 + 1280000;       // 8*160000
  float* hx1 = lx0 + 1280000;       // 8*80000
  float* lx1 = hx1 + 640000;        // 8*80000
  float* hx2 = lx1 + 640000;        // 8*40000
  float* lx2 = hx2 + 320000;        // 8*40000
  float* Aarr = lx2 + 320000;       // 4*32000  [band][frame]
  float2* wtab = (float2*)(Aarr + 4 * NFRAMES);  // 4*256 float2
  (void)ws_size;

  // QMF cascade (window tables initialized by stage 2's extra block)
  hipLaunchKernelGGL(qmf_kernel, dim3(5000), dim3(256), 0, stream, x, 320000,
                     hx0, lx0, (float2*)nullptr);
  hipLaunchKernelGGL(qmf_kernel, dim3(2500), dim3(256), 0, stream, lx0,
                     160000, hx1, lx1, (float2*)nullptr);
  hipLaunchKernelGGL(qmf_kernel, dim3(1251), dim3(256), 0, stream, lx1, 80000,
                     hx2, lx2, wtab);

  // all 4 bands, one launch
  hipLaunchKernelGGL(bands_kernel, dim3(3000), dim3(256), 0, stream, hx0, hx1,
                     hx2, lx2, f0, wtab, Aarr);

  // fused log + interp + exp
  hipLaunchKernelGGL(interp_kernel, dim3(NFRAMES / 4), dim3(256), 0, stream,
                     Aarr, out);
}

// Round 4
// 81.870 us; speedup vs baseline: 3.9913x; 1.0715x over previous
//
#include <hip/hip_runtime.h>
#include <math.h>

#define NB 8
#define NF 4000
#define NFRAMES (NB * NF)

// ---- filter taps (first half; symmetric). Double literals -> f32 at compile
// time, matching numpy float64 -> float32 conversion exactly.
__constant__ float c_hhp[21] = {
    0.00041447996898231424, 0.0007812505141729248, -0.0010917236836275842,
    -0.001986792567596759,  0.0020903896961562292, 0.004094057027284935,
    -0.0034025808529816698, -0.007496154127205602, 0.004972263339933064,
    0.012738791249119802,   -0.006696032689574911, -0.020694051570247052,
    0.008432436565041345,   0.03307438375870053,   -0.010018936738799522,
    -0.05423136140580825,   0.011293988915051487,  0.10020081367388213,
    -0.012120546202484579,  -0.316300210390957,    0.5124068258062764};
__constant__ float c_hlp[19] = {
    -0.0006548817007748305, 7.561994958159384e-05, 0.0020408456937895227,
    -0.0007468053532203044, -0.004350223568826493, 0.0025966428382642732,
    0.007639602282756696,   -0.006490411890149785, -0.011765804538954506,
    0.013649908479276255,   0.01636866479016021,   -0.026075976030529347,
    -0.020910294856659444,  0.04826072503231665,   0.02476784661104811,
    -0.09617846758336064,   -0.027359756709866623, 0.3148805216163004,
    0.5282734359405503};

__device__ __forceinline__ int reflidx(int i, int len) {
  if (i < 0) i = -i;
  if (i >= len) i = 2 * len - 2 - i;
  return i;
}
__device__ __forceinline__ int clampi(int i, int hi) {
  return min(max(i, 0), hi);
}

// ---- QMF stage: stride-2 correlation with reflect padding, both filters.
// If wtab != null, one extra block initializes the window tables (padded with
// zeros to 256 entries per band -- the band kernels rely on those zeros).
__global__ __launch_bounds__(256) void qmf_kernel(
    const float* __restrict__ in, int len, float* __restrict__ outH,
    float* __restrict__ outL, float2* __restrict__ wtab) {
  int half = len >> 1;
  int gid = blockIdx.x * 256 + threadIdx.x;
  if (gid >= NB * half) {
    if (wtab) {
      const int segs[4] = {241, 121, 61, 61};
      int k = threadIdx.x;
      for (int i = 0; i < 4; ++i) {
        float v = 0.f;
        if (k < segs[i]) {
          double ang = 2.0 * 3.14159265358979323846 * (double)(k + 1) /
                       (double)(segs[i] + 1);
          v = (float)(0.5 - 0.5 * cos(ang));
        }
        wtab[i * 256 + k] = make_float2(v, sqrtf(v));
      }
    }
    return;
  }
  int b = gid / half;
  int nn = gid - b * half;
  const float* row = in + (size_t)b * len;
  int c = 2 * nn;
  float sh = 0.f, sl = 0.f;
  if (c >= 20 && c <= len - 22) {
    const float2* p2 = reinterpret_cast<const float2*>(row + (c - 20));
    float v[42];
#pragma unroll
    for (int j = 0; j < 21; ++j) {
      float2 t = p2[j];
      v[2 * j] = t.x;
      v[2 * j + 1] = t.y;
    }
#pragma unroll
    for (int t = 0; t < 41; ++t) sh += v[t] * c_hhp[t <= 20 ? t : 40 - t];
#pragma unroll
    for (int t = 0; t < 37; ++t) sl += v[t + 2] * c_hlp[t <= 18 ? t : 36 - t];
  } else {
#pragma unroll
    for (int t = 0; t < 41; ++t)
      sh += row[reflidx(c + t - 20, len)] * c_hhp[t <= 20 ? t : 40 - t];
#pragma unroll
    for (int t = 0; t < 37; ++t)
      sl += row[reflidx(c + t - 18, len)] * c_hlp[t <= 18 ? t : 36 - t];
  }
  outH[(size_t)b * half + nn] = sh;
  outL[(size_t)b * half + nn] = sl;
}

#define ACCUM_SAMPLE()                         \
  do {                                         \
    sxx += wk * x * x;                         \
    s1x += wsk * x;                            \
    float wh0 = wk * h0, wh1 = wk * h1, wh2 = wk * h2, wh3 = wk * h3, \
          wh4 = wk * h4, wh5 = wk * h5;        \
    gv[0] += wsk * h0; gv[1] += wsk * h1; gv[2] += wsk * h2;          \
    gv[3] += wsk * h3; gv[4] += wsk * h4; gv[5] += wsk * h5;          \
    bv[0] += wh0 * x;  bv[1] += wh1 * x;  bv[2] += wh2 * x;           \
    bv[3] += wh3 * x;  bv[4] += wh4 * x;  bv[5] += wh5 * x;           \
    rr[0] += wh0 * h0;  rr[1] += wh0 * h1;  rr[2] += wh0 * h2;        \
    rr[3] += wh0 * h3;  rr[4] += wh0 * h4;  rr[5] += wh0 * h5;        \
    rr[6] += wh1 * h1;  rr[7] += wh1 * h2;  rr[8] += wh1 * h3;        \
    rr[9] += wh1 * h4;  rr[10] += wh1 * h5; rr[11] += wh2 * h2;       \
    rr[12] += wh2 * h3; rr[13] += wh2 * h4; rr[14] += wh2 * h5;       \
    rr[15] += wh3 * h3; rr[16] += wh3 * h4; rr[17] += wh3 * h5;       \
    rr[18] += wh4 * h4; rr[19] += wh4 * h5; rr[20] += wh5 * h5;       \
  } while (0)

// ---- accumulation loop: compile-time trip count NITER (zero-padded window),
// immediate-offset loads in the fast path.
template <int GS, int NITER, bool CLAMP>
__device__ __forceinline__ void acc_loop(
    const float* __restrict__ row, int T1, int base_a, int base_b, int origin,
    int sub, const float2* __restrict__ wtab, float rr[21], float bv[6],
    float gv[6], float& sxx, float& s1x) {
  if (!CLAMP) {
    const float* pa = row + base_a + sub;
    const float* pb = row + base_b + sub;
    const float* pg = row + origin + sub;
    const float2* pw = wtab + sub;
#pragma unroll 4
    for (int j = 0; j < NITER; ++j) {
      float2 wp = pw[j * GS];
      float wk = wp.x, wsk = wp.y;
      float h0 = pa[j * GS], h1 = pa[j * GS + 1], h2 = pa[j * GS + 2];
      float h3 = pb[j * GS], h4 = pb[j * GS + 1], h5 = pb[j * GS + 2];
      float x = pg[j * GS];
      ACCUM_SAMPLE();
    }
  } else {
#pragma unroll 4
    for (int j = 0; j < NITER; ++j) {
      int k = sub + j * GS;
      float2 wp = wtab[k];
      float wk = wp.x, wsk = wp.y;
      int ia = base_a + k, ib = base_b + k;
      float h0 = row[clampi(ia, T1)];
      float h1 = row[clampi(ia + 1, T1)];
      float h2 = row[clampi(ia + 2, T1)];
      float h3 = row[clampi(ib, T1)];
      float h4 = row[clampi(ib + 1, T1)];
      float h5 = row[clampi(ib + 2, T1)];
      float x = row[clampi(origin + k, T1)];
      ACCUM_SAMPLE();
    }
  }
}

// ---- per-band frame body: GS lanes per frame, NITER*GS >= SEG (zero-padded).
template <int SEG, int LGS, int NITER>
__device__ __forceinline__ void band_body(
    const float* __restrict__ xb, int bandLen, const float* __restrict__ f0,
    float tmp_fs, const float2* __restrict__ wtab, float* __restrict__ Aout,
    int blk) {
  constexpr int GS = 1 << LGS;
  constexpr int FPB = 256 / GS;
  constexpr int KMAX = NITER * GS;
  const int sub = threadIdx.x & (GS - 1);
  const int frame = blk * FPB + (threadIdx.x >> LGS);
  const int b = frame / NF;
  const int n = frame - b * NF;

  float f0v = f0[frame];
  if (f0v <= 32.0f) f0v = 150.0f;
  // replicate JAX f32 op sequence exactly (no FMA contraction):
  float pitch = tmp_fs / f0v;
  int t0 = (int)(__fadd_rn(pitch, 0.5f));
  int ibias = (int)(__fadd_rn(__fmul_rn(pitch, 0.5f), 0.5f));
  float tt = __fmul_rn((float)n, 0.005f);  // FRAME_PERIOD/SR as f32
  int curr = (int)(__fadd_rn(__fmul_rn(tt, tmp_fs), 1.5f));
  int origin = curr - ibias;
  const int T1 = bandLen - 1;
  const float* row = xb + (size_t)b * bandLen;
  const int base_a = origin - t0 - 1;
  const int base_b = origin + t0 - 1;

  float rr[21], bv[6], gv[6], sxx = 0.f, s1x = 0.f;
#pragma unroll
  for (int i = 0; i < 21; ++i) rr[i] = 0.f;
#pragma unroll
  for (int i = 0; i < 6; ++i) bv[i] = 0.f;
#pragma unroll
  for (int i = 0; i < 6; ++i) gv[i] = 0.f;

  const bool fast = (base_a >= 0) && (base_b + KMAX + 1 <= T1);
  if (fast)
    acc_loop<GS, NITER, false>(row, T1, base_a, base_b, origin, sub, wtab, rr,
                               bv, gv, sxx, s1x);
  else
    acc_loop<GS, NITER, true>(row, T1, base_a, base_b, origin, sub, wtab, rr,
                              bv, gv, sxx, s1x);

  // butterfly reduce rr + bv + sxx + s1x (29 values) within the group
#pragma unroll
  for (int off = GS / 2; off >= 1; off >>= 1) {
#pragma unroll
    for (int i = 0; i < 21; ++i) rr[i] += __shfl_xor(rr[i], off, 64);
#pragma unroll
    for (int i = 0; i < 6; ++i) bv[i] += __shfl_xor(bv[i], off, 64);
    sxx += __shfl_xor(sxx, off, 64);
    s1x += __shfl_xor(s1x, off, 64);
  }

  // Cholesky of R + 1e-5 I, solve for a (redundant across group lanes)
  float M[6][6], invd[6];
  {
    int c = 0;
#pragma unroll
    for (int p = 0; p < 6; ++p)
#pragma unroll
      for (int q = p; q < 6; ++q) {
        M[p][q] = rr[c];
        M[q][p] = rr[c];
        ++c;
      }
#pragma unroll
    for (int p = 0; p < 6; ++p) M[p][p] += 1e-5f;
  }
#pragma unroll
  for (int p = 0; p < 6; ++p) {
    float d = M[p][p];
#pragma unroll
    for (int j = 0; j < 6; ++j)
      if (j < p) d -= M[p][j] * M[p][j];
    d = sqrtf(d);
    M[p][p] = d;
    float inv = 1.0f / d;
    invd[p] = inv;
#pragma unroll
    for (int q = 0; q < 6; ++q)
      if (q > p) {
        float s = M[q][p];
#pragma unroll
        for (int j = 0; j < 6; ++j)
          if (j < p) s -= M[q][j] * M[p][j];
        M[q][p] = s * inv;
      }
  }
  float yv[6], av[6];
#pragma unroll
  for (int p = 0; p < 6; ++p) {
    float s = bv[p];
#pragma unroll
    for (int j = 0; j < 6; ++j)
      if (j < p) s -= M[p][j] * yv[j];
    yv[p] = s * invd[p];
  }
#pragma unroll
  for (int p = 5; p >= 0; --p) {
    float s = yv[p];
#pragma unroll
    for (int j = 0; j < 6; ++j)
      if (j > p) s -= M[j][p] * av[j];
    av[p] = s * invd[p];
  }

  // a.g: per-lane partial dot (gv unreduced), then reduce one scalar.
  float adotg = av[0] * gv[0] + av[1] * gv[1] + av[2] * gv[2] +
                av[3] * gv[3] + av[4] * gv[4] + av[5] * gv[5];
#pragma unroll
  for (int off = GS / 2; off >= 1; off >>= 1)
    adotg += __shfl_xor(adotg, off, 64);

  // residual stats via exact expansion (valid for ANY a):
  //   s2r = Sxx - 2 a.b + a'Ra ;  s1r = S1x - a.g   (R without eps)
  float adotb = 0.f, quad = 0.f;
  {
    int c = 0;
#pragma unroll
    for (int p = 0; p < 6; ++p) {
      adotb += av[p] * bv[p];
#pragma unroll
      for (int q = p; q < 6; ++q) {
        float t = av[p] * av[q] * rr[c++];
        quad += (q == p) ? t : 2.f * t;
      }
    }
  }
  if (sub == 0) {
    float s2r = sxx - 2.f * adotb + quad;
    float s1r = s1x - adotg;
    const float nf = (float)SEG;
    float vx = (sxx - s1x * s1x / nf) / (nf - 1.0f);
    float vr = (s2r - s1r * s1r / nf) / (nf - 1.0f);
    float sx = sqrtf(fmaxf(vx, 0.f));
    float sr = sqrtf(fmaxf(vr, 0.f));
    Aout[frame] = sr / (sx + 1e-16f);
  }
}

// ---- all 4 bands in one launch. Blocks: [0,1000) band0 GS=8 NITER=32,
// [1000,2000) band1 GS=8 NITER=16, [2000,2500) band2 GS=4 NITER=16,
// [2500,3000) band3 GS=4 NITER=16.
__global__ __launch_bounds__(256) void bands_kernel(
    const float* __restrict__ hx0, const float* __restrict__ hx1,
    const float* __restrict__ hx2, const float* __restrict__ lx2,
    const float* __restrict__ f0, const float2* __restrict__ wtab,
    float* __restrict__ Aarr) {
  int blk = blockIdx.x;
  if (blk < 1000) {
    band_body<241, 3, 32>(hx0, 160000, f0, 8000.0f, wtab + 0 * 256,
                          Aarr + 0 * NFRAMES, blk);
  } else if (blk < 2000) {
    band_body<121, 3, 16>(hx1, 80000, f0, 4000.0f, wtab + 1 * 256,
                          Aarr + 1 * NFRAMES, blk - 1000);
  } else if (blk < 2500) {
    band_body<61, 2, 16>(hx2, 40000, f0, 2000.0f, wtab + 2 * 256,
                         Aarr + 2 * NFRAMES, blk - 2000);
  } else {
    band_body<61, 2, 16>(lx2, 40000, f0, 2000.0f, wtab + 3 * 256,
                         Aarr + 3 * NFRAMES, blk - 2500);
  }
}

// ---- fused log + interpolate + exp: one wave per frame, 4 waves/block.
__global__ __launch_bounds__(256) void interp_kernel(
    const float* __restrict__ A, float* __restrict__ out) {
  const int wave = threadIdx.x >> 6;
  const int lane = threadIdx.x & 63;
  const int f = blockIdx.x * 4 + wave;
  float l0 = __logf(A[0 * NFRAMES + f]);  // band0: 8000 Hz node
  float l1 = __logf(A[1 * NFRAMES + f]);  // 4000
  float l2 = __logf(A[2 * NFRAMES + f]);  // 2000
  float l3 = __logf(A[3 * NFRAMES + f]);  // 0 & 1000 (duplicated)
  float d1 = l2 - l3, d2 = l1 - l2, d3 = l0 - l1;
  float* orow = out + (size_t)f * 513;
  for (int k = lane; k < 513; k += 64) {
    // freq = k*15.625; idx boundaries at k = 64 / 128 / 256 (exact).
    float y0, dy, c;
    int k0;
    if (k <= 64) {
      y0 = l3; dy = 0.f; k0 = 0; c = 0.015625f;        // 1/64
    } else if (k <= 128) {
      y0 = l3; dy = d1; k0 = 64; c = 0.015625f;        // 1/64
    } else if (k <= 256) {
      y0 = l2; dy = d2; k0 = 128; c = 0.0078125f;      // 1/128
    } else {
      y0 = l1; dy = d3; k0 = 256; c = 0.00390625f;     // 1/256
    }
    float w = (float)(k - k0) * c;  // exact (matches f64-computed _WTS)
    orow[k] = __expf(y0 + w * dy);
  }
}

extern "C" void kernel_launch(void* const* d_in, const int* in_sizes, int n_in,
                              void* d_out, int out_size, void* d_ws,
                              size_t ws_size, hipStream_t stream) {
  const float* x = (const float*)d_in[0];   // (8, 320000)
  const float* f0 = (const float*)d_in[1];  // (8, 4000)
  float* out = (float*)d_out;               // (8, 4000, 513)
  float* ws = (float*)d_ws;

  // workspace layout (floats)
  float* hx0 = ws + 0;              // 8*160000
  float* lx0 = hx0 + 1280000;       // 8*160000
  float* hx1 = lx0 + 1280000;       // 8*80000
  float* lx1 = hx1 + 640000;        // 8*80000
  float* hx2 = lx1 + 640000;        // 8*40000
  float* lx2 = hx2 + 320000;        // 8*40000
  float* Aarr = lx2 + 320000;       // 4*32000  [band][frame]
  float2* wtab = (float2*)(Aarr + 4 * NFRAMES);  // 4*256 float2
  (void)ws_size;

  // QMF cascade (window tables initialized by stage 2's extra block)
  hipLaunchKernelGGL(qmf_kernel, dim3(5000), dim3(256), 0, stream, x, 320000,
                     hx0, lx0, (float2*)nullptr);
  hipLaunchKernelGGL(qmf_kernel, dim3(2500), dim3(256), 0, stream, lx0,
                     160000, hx1, lx1, (float2*)nullptr);
  hipLaunchKernelGGL(qmf_kernel, dim3(1251), dim3(256), 0, stream, lx1, 80000,
                     hx2, lx2, wtab);

  // all 4 bands, one launch
  hipLaunchKernelGGL(bands_kernel, dim3(3000), dim3(256), 0, stream, hx0, hx1,
                     hx2, lx2, f0, wtab, Aarr);

  // fused log + interp + exp
  hipLaunchKernelGGL(interp_kernel, dim3(NFRAMES / 4), dim3(256), 0, stream,
                     Aarr, out);
}